// Round 7
// baseline (3018.452 us; speedup 1.0000x reference)
//
#include <hip/hip_runtime.h>
#include <stdint.h>

typedef __attribute__((ext_vector_type(8))) _Float16 half8;
typedef __attribute__((ext_vector_type(4))) float f32x4;
typedef __attribute__((ext_vector_type(4))) uint32_t uint4v;

#define LR 0.1f
#define BLOCK 256
#define PERM __builtin_amdgcn_perm

// LDS byte offsets
// WFRAG: [9 layers][2 dir][3 tiles][2 ks][64 lanes][16B] = 110592
#define WOUTP_OFF  110592   // pred B-frags: [2 ks][64][16B] = 2048
#define WOUTT_OFF  112640   // td10 B-frags: [3 tiles][64][16B] = 3072
#define BH_OFF_B   115712   // bh f32: 9*48*4 = 1728
#define BOUT_OFF_B 117440   // bout f32: 64
#define VT_OFF_B   117504   // per-wave: 2 groups x 3456 B transpose tiles
#define VT_TILE    3456
#define VT_WAVE    6912
#define LDS_BYTES  (VT_OFF_B + 4*VT_WAVE)   // 145152

extern __shared__ unsigned char smem[];

#define F16BITS(VAL) ((uint32_t)__builtin_bit_cast(unsigned short, (_Float16)(VAL)))

// pack f32 -> (f16 hi << 16) | f16 lo  (2-term split)
#define PACK_SPLIT(VAL, W) do { \
  float _v0 = (VAL); \
  _Float16 _hh = (_Float16)_v0; \
  float _hf = (float)_hh; \
  W = (F16BITS(_v0 - _hf)) | ((uint32_t)__builtin_bit_cast(unsigned short, _hh) << 16); \
} while(0)

#define GATHER_HI(WA, WB, HU) do { \
  HU[0] = PERM(WA[1], WA[0], 0x07060302u); \
  HU[1] = PERM(WA[3], WA[2], 0x07060302u); \
  HU[2] = PERM(WB[1], WB[0], 0x07060302u); \
  HU[3] = PERM(WB[3], WB[2], 0x07060302u); \
} while(0)
#define GATHER_LO(WA, WB, LU) do { \
  LU[0] = PERM(WA[1], WA[0], 0x05040100u); \
  LU[1] = PERM(WA[3], WA[2], 0x05040100u); \
  LU[2] = PERM(WB[1], WB[0], 0x05040100u); \
  LU[3] = PERM(WB[3], WB[2], 0x05040100u); \
} while(0)

// pack one group's 12 values into its VT tile (C-layout -> [sample][comp])
#define PACK12(SRC, VTU, SPLIT) do { \
  _Pragma("unroll") \
  for (int _t = 0; _t < 3; ++_t) { \
    _Pragma("unroll") \
    for (int _r = 0; _r < 4; ++_r) { \
      uint32_t _w; \
      if (SPLIT) { PACK_SPLIT(SRC[_t*4+_r], _w); } \
      else { _w = F16BITS(SRC[_t*4+_r]) << 16; } \
      (VTU)[(4*bq+_r)*52 + n + 16*_t] = _w; \
    } \
  } \
} while(0)

// read one group's A-fragments from its VT tile
#define READA(VTU, AH0, AH1, AL0, AL1, SPLIT) do { \
  { \
    const uint32_t* _vp = (VTU) + n*52 + bq*8; \
    uint4v _wa = *(const uint4v*)_vp; \
    uint4v _wb = *(const uint4v*)(_vp + 4); \
    uint4v _hu; GATHER_HI(_wa, _wb, _hu); AH0 = __builtin_bit_cast(half8, _hu); \
    if (SPLIT) { uint4v _lu; GATHER_LO(_wa, _wb, _lu); AL0 = __builtin_bit_cast(half8, _lu); } \
  } \
  { \
    const uint32_t* _vp = (VTU) + n*52 + 32 + bq*8; \
    uint4v _wa = *(const uint4v*)_vp; \
    uint4v _wb = *(const uint4v*)(_vp + 4); \
    uint4v _hu; GATHER_HI(_wa, _wb, _hu); AH1 = __builtin_bit_cast(half8, _hu); \
    if (SPLIT) { uint4v _lu; GATHER_LO(_wa, _wb, _lu); AL1 = __builtin_bit_cast(half8, _lu); } \
  } \
} while(0)

// 3-tile MFMA sweep for one group (uses _B00.._B21, _bv0.._bv2 from MV48PAIR scope)
#define MFMA3T(AH0, AH1, AL0, AL1, DST, SPLIT) do { \
  { \
    f32x4 _acc = { _bv0, _bv0, _bv0, _bv0 }; \
    _acc = __builtin_amdgcn_mfma_f32_16x16x32_f16(AH0, _B00, _acc, 0, 0, 0); \
    if (SPLIT) _acc = __builtin_amdgcn_mfma_f32_16x16x32_f16(AL0, _B00, _acc, 0, 0, 0); \
    _acc = __builtin_amdgcn_mfma_f32_16x16x32_f16(AH1, _B01, _acc, 0, 0, 0); \
    if (SPLIT) _acc = __builtin_amdgcn_mfma_f32_16x16x32_f16(AL1, _B01, _acc, 0, 0, 0); \
    _Pragma("unroll") \
    for (int _r = 0; _r < 4; ++_r) DST[0*4+_r] = _acc[_r]; \
  } \
  { \
    f32x4 _acc = { _bv1, _bv1, _bv1, _bv1 }; \
    _acc = __builtin_amdgcn_mfma_f32_16x16x32_f16(AH0, _B10, _acc, 0, 0, 0); \
    if (SPLIT) _acc = __builtin_amdgcn_mfma_f32_16x16x32_f16(AL0, _B10, _acc, 0, 0, 0); \
    _acc = __builtin_amdgcn_mfma_f32_16x16x32_f16(AH1, _B11, _acc, 0, 0, 0); \
    if (SPLIT) _acc = __builtin_amdgcn_mfma_f32_16x16x32_f16(AL1, _B11, _acc, 0, 0, 0); \
    _Pragma("unroll") \
    for (int _r = 0; _r < 4; ++_r) DST[1*4+_r] = _acc[_r]; \
  } \
  { \
    f32x4 _acc = { _bv2, _bv2, _bv2, _bv2 }; \
    _acc = __builtin_amdgcn_mfma_f32_16x16x32_f16(AH0, _B20, _acc, 0, 0, 0); \
    if (SPLIT) _acc = __builtin_amdgcn_mfma_f32_16x16x32_f16(AL0, _B20, _acc, 0, 0, 0); \
    _acc = __builtin_amdgcn_mfma_f32_16x16x32_f16(AH1, _B21, _acc, 0, 0, 0); \
    if (SPLIT) _acc = __builtin_amdgcn_mfma_f32_16x16x32_f16(AL1, _B21, _acc, 0, 0, 0); \
    _Pragma("unroll") \
    for (int _r = 0; _r < 4; ++_r) DST[2*4+_r] = _acc[_r]; \
  } \
} while(0)

// paired 48x48 matvec: two groups share B-frags/biases; chains interleave
#define MV48PAIR(SRC0, SRC1, WFB, BIASOFF, HASBIAS, SPLIT, DST0, DST1) do { \
  half8 _B00 = *(const half8*)(smem + (WFB) + 0*1024 + lane*16); \
  half8 _B01 = *(const half8*)(smem + (WFB) + 1*1024 + lane*16); \
  half8 _B10 = *(const half8*)(smem + (WFB) + 2*1024 + lane*16); \
  half8 _B11 = *(const half8*)(smem + (WFB) + 3*1024 + lane*16); \
  half8 _B20 = *(const half8*)(smem + (WFB) + 4*1024 + lane*16); \
  half8 _B21 = *(const half8*)(smem + (WFB) + 5*1024 + lane*16); \
  float _bv0 = (HASBIAS) ? bhf[(BIASOFF) + n]      : 0.f; \
  float _bv1 = (HASBIAS) ? bhf[(BIASOFF) + n + 16] : 0.f; \
  float _bv2 = (HASBIAS) ? bhf[(BIASOFF) + n + 32] : 0.f; \
  PACK12(SRC0, vtu0, SPLIT); \
  PACK12(SRC1, vtu1, SPLIT); \
  __builtin_amdgcn_fence(__ATOMIC_ACQ_REL, "wavefront"); \
  half8 _xAh0, _xAh1, _xAl0 = {}, _xAl1 = {}; \
  half8 _yAh0, _yAh1, _yAl0 = {}, _yAl1 = {}; \
  READA(vtu0, _xAh0, _xAh1, _xAl0, _xAl1, SPLIT); \
  READA(vtu1, _yAh0, _yAh1, _yAl0, _yAl1, SPLIT); \
  MFMA3T(_xAh0, _xAh1, _xAl0, _xAl1, DST0, SPLIT); \
  MFMA3T(_yAh0, _yAh1, _yAl0, _yAl1, DST1, SPLIT); \
} while(0)

#define LAYER_STEP(I) do { \
  float _pre0[12], _pre1[12], _me0[12], _me1[12], _td0[12], _td1[12]; \
  MV48PAIR(v0[(I)-1], v1[(I)-1], ((I)-1)*12288, ((I)-1)*48, 1, 1, _pre0, _pre1); \
  float _err0[12], _err1[12]; \
  _Pragma("unroll") \
  for (int _q = 0; _q < 12; ++_q) { \
    float _rl0 = fmaxf(_pre0[_q], 0.f); \
    _err0[_q] = v0[I][_q] - _rl0; \
    _me0[_q] = (_pre0[_q] > 0.f) ? _err0[_q] : 0.f; \
    float _rl1 = fmaxf(_pre1[_q], 0.f); \
    _err1[_q] = v1[I][_q] - _rl1; \
    _me1[_q] = (_pre1[_q] > 0.f) ? _err1[_q] : 0.f; \
  } \
  MV48PAIR(_me0, _me1, ((I)-1)*12288 + 6144, 0, 0, 0, _td0, _td1); \
  _Pragma("unroll") \
  for (int _q = 0; _q < 12; ++_q) { \
    float _nv0 = v0[(I)-1][_q] - LR*(ep0[_q] - _td0[_q]); \
    v0[(I)-1][_q] = fminf(fmaxf(_nv0, -10.f), 10.f); \
    ep0[_q] = _err0[_q]; \
    float _nv1 = v1[(I)-1][_q] - LR*(ep1[_q] - _td1[_q]); \
    v1[(I)-1][_q] = fminf(fmaxf(_nv1, -10.f), 10.f); \
    ep1[_q] = _err1[_q]; \
  } \
} while(0)

#define FWDP(I) do { \
  float _pre0[12], _pre1[12]; \
  MV48PAIR(v0[(I)-1], v1[(I)-1], ((I)-1)*12288, ((I)-1)*48, 1, 1, _pre0, _pre1); \
  _Pragma("unroll") \
  for (int _q = 0; _q < 12; ++_q) { \
    v0[I][_q] = fmaxf(_pre0[_q], 0.f); \
    v1[I][_q] = fmaxf(_pre1[_q], 0.f); \
  } \
} while(0)

__global__ __launch_bounds__(BLOCK) __attribute__((amdgpu_waves_per_eu(1, 1)))
void pcnet_kernel(const float* __restrict__ x, const int* __restrict__ target,
                  const float* __restrict__ W0, const float* __restrict__ b0,
                  const float* __restrict__ Wh, const float* __restrict__ bh,
                  const float* __restrict__ Wout, const float* __restrict__ bout,
                  float* __restrict__ out)
{
    const int t = threadIdx.x;
    const int lane = t & 63;
    const int wv = t >> 6;
    float* ldsf = (float*)smem;
    const float* bhf = (const float*)(smem + BH_OFF_B);
    const float* boutf = (const float*)(smem + BOUT_OFF_B);

    const int bsamp0 = blockIdx.x*128 + wv*32;   // wave's first sample (2 groups x 16)

    // ======== phase 0: a0 = relu(x@W0^T + b0), both groups, 4-lane-quarter map ====
    const int g = lane & 3, sloc = lane >> 2;
    const int j0 = g*12;
    const int bOld0 = bsamp0 + sloc;
    const int bOld1 = bsamp0 + 16 + sloc;
    float accg0[12], accg1[12];
    #pragma unroll
    for (int jj = 0; jj < 12; jj++) { accg0[jj] = b0[j0+jj]; accg1[jj] = accg0[jj]; }
    for (int ch = 0; ch < 7; ch++) {
        __syncthreads();
        for (int idx = t; idx < 112*48; idx += BLOCK) {
            int j = idx / 112, kl = idx - j*112;
            ldsf[kl*48 + j] = W0[j*784 + ch*112 + kl];
        }
        __syncthreads();
        const float* xb0 = x + (size_t)bOld0*784 + ch*112;
        const float* xb1 = x + (size_t)bOld1*784 + ch*112;
        for (int k4 = 0; k4 < 112; k4 += 4) {
            float4 xv0 = *(const float4*)(xb0 + k4);
            float4 xv1 = *(const float4*)(xb1 + k4);
            float xs0[4] = {xv0.x, xv0.y, xv0.z, xv0.w};
            float xs1[4] = {xv1.x, xv1.y, xv1.z, xv1.w};
            #pragma unroll
            for (int f = 0; f < 4; f++) {
                const float* wr = &ldsf[(k4+f)*48 + j0];
                #pragma unroll
                for (int jj = 0; jj < 12; jj++) {
                    accg0[jj] = fmaf(wr[jj], xs0[f], accg0[jj]);
                    accg1[jj] = fmaf(wr[jj], xs1[f], accg1[jj]);
                }
            }
        }
    }

    // remap a0 -> C-layout via per-wave VT tiles
    float* vtf0 = (float*)(smem + VT_OFF_B + wv*VT_WAVE);
    float* vtf1 = (float*)(smem + VT_OFF_B + wv*VT_WAVE + VT_TILE);
    uint32_t* vtu0 = (uint32_t*)vtf0;
    uint32_t* vtu1 = (uint32_t*)vtf1;
    #pragma unroll
    for (int jj = 0; jj < 12; jj++) {
        vtf0[sloc*52 + j0 + jj] = fmaxf(accg0[jj], 0.f);
        vtf1[sloc*52 + j0 + jj] = fmaxf(accg1[jj], 0.f);
    }
    __builtin_amdgcn_fence(__ATOMIC_ACQ_REL, "wavefront");

    const int bq = lane >> 4;    // 0..3: sample block in frag
    const int n  = lane & 15;    // col within tile
    float v0[10][12], v1[10][12], a0r0[12], a0r1[12];
    #pragma unroll
    for (int tt = 0; tt < 3; tt++)
        #pragma unroll
        for (int r = 0; r < 4; r++) {
            float val0 = vtf0[(4*bq+r)*52 + n + 16*tt];
            float val1 = vtf1[(4*bq+r)*52 + n + 16*tt];
            a0r0[tt*4+r] = val0; v0[0][tt*4+r] = val0;
            a0r1[tt*4+r] = val1; v1[0][tt*4+r] = val1;
        }

    // zero VT pad cols 48..51 and tail pad in both tiles (keep MFMA reads finite)
    vtu0[(lane>>2)*52 + 48 + (lane&3)] = 0u;
    vtu1[(lane>>2)*52 + 48 + (lane&3)] = 0u;
    if (lane < 32) { vtu0[832 + lane] = 0u; vtu1[832 + lane] = 0u; }

    __syncthreads();

    // ======== stage weight frags (f16, frag-order: conflict-free 16B/lane) ========
    for (int slot = t; slot < 6912; slot += BLOCK) {
        int L = slot / 768; int rem = slot % 768;
        int dir = rem / 384; rem %= 384;
        int tl = rem / 128; rem %= 128;
        int ks = rem / 64; int LB = rem % 64;
        int row = tl*16 + (LB & 15);
        int k0 = ks*32 + (LB >> 4)*8;
        half8 hv;
        #pragma unroll
        for (int j = 0; j < 8; j++) {
            int k = k0 + j;
            float w = 0.f;
            if (k < 48) w = (dir == 0) ? Wh[L*2304 + row*48 + k] : Wh[L*2304 + k*48 + row];
            hv[j] = (_Float16)w;
        }
        *(half8*)(smem + (L*2+dir)*6144 + (tl*2+ks)*1024 + LB*16) = hv;
    }
    for (int slot = t; slot < 5*64; slot += BLOCK) {
        int which = slot / 64; int LB = slot % 64;
        half8 hv;
        if (which < 2) {          // pred B: ks = which; rows = out class c
            int c = LB & 15; int k0 = which*32 + (LB>>4)*8;
            #pragma unroll
            for (int j = 0; j < 8; j++) { int k = k0+j; hv[j] = (_Float16)((c < 10 && k < 48) ? Wout[c*48+k] : 0.f); }
            *(half8*)(smem + WOUTP_OFF + which*1024 + LB*16) = hv;
        } else {                  // td10 B tiles: rows = hidden comp, K = class (pad 32)
            int tl = which - 2; int row = tl*16 + (LB & 15); int c0 = (LB>>4)*8;
            #pragma unroll
            for (int j = 0; j < 8; j++) { int c = c0+j; hv[j] = (_Float16)((c < 10) ? Wout[c*48+row] : 0.f); }
            *(half8*)(smem + WOUTT_OFF + tl*1024 + LB*16) = hv;
        }
    }
    for (int idx = t; idx < 432; idx += BLOCK) ((float*)(smem+BH_OFF_B))[idx] = bh[idx];
    if (t < 10) ((float*)(smem+BOUT_OFF_B))[t] = bout[t];
    __syncthreads();

    // targets for this lane's samples (both groups)
    int tg0[4], tg1[4];
    #pragma unroll
    for (int r = 0; r < 4; r++) {
        tg0[r] = target[bsamp0 + 4*bq + r];
        tg1[r] = target[bsamp0 + 16 + 4*bq + r];
    }

    // ======== forward init layers 1..9 ========
    FWDP(1); FWDP(2); FWDP(3); FWDP(4); FWDP(5); FWDP(6); FWDP(7); FWDP(8); FWDP(9);

    // ======== settling ========
    #pragma unroll 1
    for (int s = 0; s < 20; ++s) {
        float ep0[12], ep1[12];
        #pragma unroll
        for (int q = 0; q < 12; q++) {
            ep0[q] = v0[0][q] - a0r0[q];
            ep1[q] = v1[0][q] - a0r1[q];
        }

        LAYER_STEP(1); LAYER_STEP(2); LAYER_STEP(3); LAYER_STEP(4); LAYER_STEP(5);
        LAYER_STEP(6); LAYER_STEP(7); LAYER_STEP(8); LAYER_STEP(9);

        // ---- output layer (single-f16: LR-damped), both groups ----
        {
            half8 Bp0 = *(const half8*)(smem + WOUTP_OFF + lane*16);
            half8 Bp1 = *(const half8*)(smem + WOUTP_OFF + 1024 + lane*16);
            half8 Bt0 = *(const half8*)(smem + WOUTT_OFF + 0*1024 + lane*16);
            half8 Bt1 = *(const half8*)(smem + WOUTT_OFF + 1*1024 + lane*16);
            half8 Bt2 = *(const half8*)(smem + WOUTT_OFF + 2*1024 + lane*16);
            PACK12(v0[9], vtu0, 0);
            PACK12(v1[9], vtu1, 0);
            __builtin_amdgcn_fence(__ATOMIC_ACQ_REL, "wavefront");
            half8 xAh0, xAh1, yAh0, yAh1;
            {
                half8 d0 = {}, d1 = {};
                READA(vtu0, xAh0, xAh1, d0, d1, 0);
                READA(vtu1, yAh0, yAh1, d0, d1, 0);
            }
            float bo = (n < 10) ? boutf[n] : 0.f;
            f32x4 acc0 = {bo, bo, bo, bo};
            f32x4 acc1 = {bo, bo, bo, bo};
            acc0 = __builtin_amdgcn_mfma_f32_16x16x32_f16(xAh0, Bp0, acc0, 0, 0, 0);
            acc0 = __builtin_amdgcn_mfma_f32_16x16x32_f16(xAh1, Bp1, acc0, 0, 0, 0);
            acc1 = __builtin_amdgcn_mfma_f32_16x16x32_f16(yAh0, Bp0, acc1, 0, 0, 0);
            acc1 = __builtin_amdgcn_mfma_f32_16x16x32_f16(yAh1, Bp1, acc1, 0, 0, 0);
            // e10 -> VT cols 0..15 (cols 16..31 stale-but-finite; B rows c>=10 zero)
            #pragma unroll
            for (int r = 0; r < 4; r++) {
                float e0 = 0.f, e1 = 0.f;
                if (n < 10) {
                    e0 = ((n == tg0[r]) ? 1.f : 0.f) - acc0[r];
                    e1 = ((n == tg1[r]) ? 1.f : 0.f) - acc1[r];
                }
                vtu0[(4*bq+r)*52 + n] = F16BITS(e0) << 16;
                vtu1[(4*bq+r)*52 + n] = F16BITS(e1) << 16;
            }
            __builtin_amdgcn_fence(__ATOMIC_ACQ_REL, "wavefront");
            half8 eAx, eAy;
            {
                const uint32_t* vp = vtu0 + n*52 + bq*8;
                uint4v wa = *(const uint4v*)vp;
                uint4v wb = *(const uint4v*)(vp + 4);
                uint4v hu; GATHER_HI(wa, wb, hu); eAx = __builtin_bit_cast(half8, hu);
                vp = vtu1 + n*52 + bq*8;
                wa = *(const uint4v*)vp;
                wb = *(const uint4v*)(vp + 4);
                uint4v hu2; GATHER_HI(wa, wb, hu2); eAy = __builtin_bit_cast(half8, hu2);
            }
            float td0[12], td1[12];
            {
                f32x4 a2 = {0.f,0.f,0.f,0.f};
                a2 = __builtin_amdgcn_mfma_f32_16x16x32_f16(eAx, Bt0, a2, 0, 0, 0);
                #pragma unroll
                for (int r = 0; r < 4; r++) td0[r] = a2[r];
            }
            {
                f32x4 a2 = {0.f,0.f,0.f,0.f};
                a2 = __builtin_amdgcn_mfma_f32_16x16x32_f16(eAx, Bt1, a2, 0, 0, 0);
                #pragma unroll
                for (int r = 0; r < 4; r++) td0[4+r] = a2[r];
            }
            {
                f32x4 a2 = {0.f,0.f,0.f,0.f};
                a2 = __builtin_amdgcn_mfma_f32_16x16x32_f16(eAx, Bt2, a2, 0, 0, 0);
                #pragma unroll
                for (int r = 0; r < 4; r++) td0[8+r] = a2[r];
            }
            {
                f32x4 a2 = {0.f,0.f,0.f,0.f};
                a2 = __builtin_amdgcn_mfma_f32_16x16x32_f16(eAy, Bt0, a2, 0, 0, 0);
                #pragma unroll
                for (int r = 0; r < 4; r++) td1[r] = a2[r];
            }
            {
                f32x4 a2 = {0.f,0.f,0.f,0.f};
                a2 = __builtin_amdgcn_mfma_f32_16x16x32_f16(eAy, Bt1, a2, 0, 0, 0);
                #pragma unroll
                for (int r = 0; r < 4; r++) td1[4+r] = a2[r];
            }
            {
                f32x4 a2 = {0.f,0.f,0.f,0.f};
                a2 = __builtin_amdgcn_mfma_f32_16x16x32_f16(eAy, Bt2, a2, 0, 0, 0);
                #pragma unroll
                for (int r = 0; r < 4; r++) td1[8+r] = a2[r];
            }
            #pragma unroll
            for (int q = 0; q < 12; q++) {
                float nv0 = v0[9][q] - LR*(ep0[q] - td0[q]);
                v0[9][q] = fminf(fmaxf(nv0, -10.f), 10.f);
                float nv1 = v1[9][q] - LR*(ep1[q] - td1[q]);
                v1[9][q] = fminf(fmaxf(nv1, -10.f), 10.f);
            }
        }
    }

    // ======== write V (both groups) ========
    #pragma unroll
    for (int L2 = 0; L2 < 10; L2++)
        #pragma unroll
        for (int tt = 0; tt < 3; tt++)
            #pragma unroll
            for (int r = 0; r < 4; r++) {
                out[(size_t)L2*65536*48 + (size_t)(bsamp0 + 4*bq + r)*48 + n + 16*tt] = v0[L2][tt*4+r];
                out[(size_t)L2*65536*48 + (size_t)(bsamp0 + 16 + 4*bq + r)*48 + n + 16*tt] = v1[L2][tt*4+r];
            }
}

extern "C" void kernel_launch(void* const* d_in, const int* in_sizes, int n_in,
                              void* d_out, int out_size, void* d_ws, size_t ws_size,
                              hipStream_t stream) {
    const float* x      = (const float*)d_in[0];
    const int*   target = (const int*)d_in[1];
    const float* W0     = (const float*)d_in[2];
    const float* b0     = (const float*)d_in[3];
    const float* Wh     = (const float*)d_in[4];
    const float* bh     = (const float*)d_in[5];
    const float* Wout   = (const float*)d_in[6];
    const float* bout   = (const float*)d_in[7];
    float* out = (float*)d_out;

    hipFuncSetAttribute((const void*)pcnet_kernel,
                        hipFuncAttributeMaxDynamicSharedMemorySize, LDS_BYTES);

    dim3 grid(65536/128);   // 512 blocks, 128 samples each (4 waves x 32)
    dim3 block(BLOCK);      // 256 threads
    pcnet_kernel<<<grid, block, LDS_BYTES, stream>>>(x, target, W0, b0, Wh, bh, Wout, bout, out);
}

// Round 9
// 1185.226 us; speedup vs baseline: 2.5467x; 2.5467x over previous
//
#include <hip/hip_runtime.h>
#include <stdint.h>

typedef __attribute__((ext_vector_type(4))) _Float16 half4;
typedef __attribute__((ext_vector_type(4))) float f32x4;

#define LR 0.1f
#define BLOCK 256
#define MFMA16 __builtin_amdgcn_mfma_f32_16x16x16f16

// LDS byte offsets
#define WH_OFF    0         // [9L][2dir][9 subtile(tm*3+ks)][64 lane][8B] = 82944
#define WOUTP_OFF 82944     // pred10 A-frags: 3 ks x 512 = 1536
#define WOUTT_OFF 84480     // td10  A-frags: 3 tm x 512 = 1536
#define BH_OFF    86016     // bh f32 9*48 = 1728
#define BOUT_OFF  87744     // bout f32 padded 16 = 64
#define LDS_BYTES 87808

extern __shared__ unsigned char smem[];

// build half4 from 4 floats, RNE scalar casts (SSA vector inserts, no alloca)
#define PACK4(S0,S1,S2,S3) __extension__({ \
  half4 _b; \
  _b[0] = (_Float16)(S0); _b[1] = (_Float16)(S1); \
  _b[2] = (_Float16)(S2); _b[3] = (_Float16)(S3); \
  _b; })

// pred-direction 48x48 matvec, f16 2-term split on values (B), bias from bh.
// D[comp 16tm+4b+q][own sample] accumulates into DST[tm*4+q] -- state layout.
#define PRED48(SRC, WOFF, LIDX, DST) do { \
  half4 _Bh[3], _Bl[3]; \
  _Pragma("unroll") \
  for (int _ks = 0; _ks < 3; ++_ks) { \
    _Float16 _h0 = (_Float16)SRC[_ks*4+0]; \
    _Float16 _h1 = (_Float16)SRC[_ks*4+1]; \
    _Float16 _h2 = (_Float16)SRC[_ks*4+2]; \
    _Float16 _h3 = (_Float16)SRC[_ks*4+3]; \
    half4 _bh; _bh[0]=_h0; _bh[1]=_h1; _bh[2]=_h2; _bh[3]=_h3; \
    half4 _bl; \
    _bl[0] = (_Float16)(SRC[_ks*4+0] - (float)_h0); \
    _bl[1] = (_Float16)(SRC[_ks*4+1] - (float)_h1); \
    _bl[2] = (_Float16)(SRC[_ks*4+2] - (float)_h2); \
    _bl[3] = (_Float16)(SRC[_ks*4+3] - (float)_h3); \
    _Bh[_ks] = _bh; _Bl[_ks] = _bl; \
  } \
  _Pragma("unroll") \
  for (int _tm = 0; _tm < 3; ++_tm) { \
    f32x4 _acc = *(const f32x4*)(smem + BH_OFF + ((LIDX)*48 + _tm*16)*4 + b*16); \
    _Pragma("unroll") \
    for (int _ks = 0; _ks < 3; ++_ks) { \
      half4 _A = *(const half4*)(smem + (WOFF) + (_tm*3+_ks)*512 + lane*8); \
      _acc = MFMA16(_A, _Bh[_ks], _acc, 0, 0, 0); \
      _acc = MFMA16(_A, _Bl[_ks], _acc, 0, 0, 0); \
    } \
    _Pragma("unroll") \
    for (int _q = 0; _q < 4; ++_q) DST[_tm*4+_q] = _acc[_q]; \
  } \
} while(0)

// td-direction 48x48 matvec, single f16 (LR-damped), no bias.
#define TD48(SRC, WOFF, DST) do { \
  half4 _B[3]; \
  _Pragma("unroll") \
  for (int _ks = 0; _ks < 3; ++_ks) \
    _B[_ks] = PACK4(SRC[_ks*4+0], SRC[_ks*4+1], SRC[_ks*4+2], SRC[_ks*4+3]); \
  _Pragma("unroll") \
  for (int _tm = 0; _tm < 3; ++_tm) { \
    f32x4 _acc = {0.f, 0.f, 0.f, 0.f}; \
    _Pragma("unroll") \
    for (int _ks = 0; _ks < 3; ++_ks) { \
      half4 _A = *(const half4*)(smem + (WOFF) + (_tm*3+_ks)*512 + lane*8); \
      _acc = MFMA16(_A, _B[_ks], _acc, 0, 0, 0); \
    } \
    _Pragma("unroll") \
    for (int _q = 0; _q < 4; ++_q) DST[_tm*4+_q] = _acc[_q]; \
  } \
} while(0)

#define LAYER_STEP(I) do { \
  float _pre[12], _err[12], _me[12], _td[12]; \
  PRED48(v[(I)-1], WH_OFF + ((I)-1)*9216, (I)-1, _pre); \
  _Pragma("unroll") \
  for (int _q = 0; _q < 12; ++_q) { \
    float _rl = fmaxf(_pre[_q], 0.f); \
    _err[_q] = v[I][_q] - _rl; \
    _me[_q] = (_pre[_q] > 0.f) ? _err[_q] : 0.f; \
  } \
  TD48(_me, WH_OFF + ((I)-1)*9216 + 4608, _td); \
  _Pragma("unroll") \
  for (int _q = 0; _q < 12; ++_q) { \
    float _nv = v[(I)-1][_q] - LR*(ep[_q] - _td[_q]); \
    v[(I)-1][_q] = fminf(fmaxf(_nv, -10.f), 10.f); \
    ep[_q] = _err[_q]; \
  } \
} while(0)

#define FWD(I) do { \
  float _pre[12]; \
  PRED48(v[(I)-1], WH_OFF + ((I)-1)*9216, (I)-1, _pre); \
  _Pragma("unroll") \
  for (int _q = 0; _q < 12; ++_q) v[I][_q] = fmaxf(_pre[_q], 0.f); \
} while(0)

__global__ __launch_bounds__(BLOCK) __attribute__((amdgpu_waves_per_eu(1, 1)))
void pcnet_kernel(const float* __restrict__ x, const int* __restrict__ target,
                  const float* __restrict__ W0, const float* __restrict__ b0,
                  const float* __restrict__ Wh, const float* __restrict__ bh,
                  const float* __restrict__ Wout, const float* __restrict__ bout,
                  float* __restrict__ out)
{
    const int t = threadIdx.x;
    const int lane = t & 63;
    const int wv = t >> 6;
    const int n = lane & 15;    // own sample within wave
    const int b = lane >> 4;    // comp sub-block 0..3 (owns comps 16t+4b+q)

    const int bsamp0 = blockIdx.x*64 + wv*16;   // wave's first sample
    const int samp = bsamp0 + n;

    // ======== phase 0: a0 = relu(x@W0^T + b0) via MFMA; x is B-operand ========
    // A-frags of W0 staged per 112-k chunk (3 tm x 7 ks x 512 B = 10752 B in WH area)
    f32x4 acc0[3];
    #pragma unroll
    for (int tm = 0; tm < 3; ++tm) acc0[tm] = (f32x4){0.f, 0.f, 0.f, 0.f};

    const float* xrow = x + (size_t)samp*784;
    for (int ch = 0; ch < 7; ++ch) {
        __syncthreads();
        for (int idx = t; idx < 1344; idx += BLOCK) {
            int st = idx >> 6, LB = idx & 63;
            int tm = st / 7, ksl = st - tm*7;
            int row = 16*tm + (LB & 15);
            int col = ch*112 + ksl*16 + 4*(LB >> 4);
            float4 w4 = *(const float4*)(W0 + row*784 + col);
            *(half4*)(smem + (tm*7+ksl)*512 + LB*8) = PACK4(w4.x, w4.y, w4.z, w4.w);
        }
        __syncthreads();
        #pragma unroll
        for (int ksl = 0; ksl < 7; ++ksl) {
            float4 xv = *(const float4*)(xrow + ch*112 + ksl*16 + 4*b);
            half4 xb = PACK4(xv.x, xv.y, xv.z, xv.w);
            #pragma unroll
            for (int tm = 0; tm < 3; ++tm) {
                half4 A = *(const half4*)(smem + (tm*7+ksl)*512 + lane*8);
                acc0[tm] = MFMA16(A, xb, acc0[tm], 0, 0, 0);
            }
        }
    }

    float v[10][12], a0r[12];
    #pragma unroll
    for (int tm = 0; tm < 3; ++tm) {
        float4 bb = *(const float4*)(b0 + 16*tm + 4*b);
        float bs[4] = {bb.x, bb.y, bb.z, bb.w};
        #pragma unroll
        for (int q = 0; q < 4; ++q) {
            float val = fmaxf(acc0[tm][q] + bs[q], 0.f);
            a0r[tm*4+q] = val; v[0][tm*4+q] = val;
        }
    }
    __syncthreads();   // phase-0 reads done before WH staging overwrites

    // ======== stage weight A-frags (f16, K16 layout, conflict-free 8B/lane) ====
    for (int idx = t; idx < 10368; idx += BLOCK) {
        int L = idx / 1152;
        int r1 = idx - L*1152;
        int dir = r1 / 576;
        int r2 = r1 - dir*576;
        int st = r2 >> 6, LB = r2 & 63;
        int tm = st / 3, ks = st - tm*3;
        int m  = 16*tm + (LB & 15);
        int k0 = 16*ks + 4*(LB >> 4);
        half4 w;
        if (dir == 0) {   // pred: A[m][k] = Wh[L][m][k]
            float4 w4 = *(const float4*)(Wh + L*2304 + m*48 + k0);
            w = PACK4(w4.x, w4.y, w4.z, w4.w);
        } else {          // td:   A[m][k] = Wh[L][k][m]
            const float* p = Wh + L*2304 + k0*48 + m;
            w = PACK4(p[0], p[48], p[96], p[144]);
        }
        *(half4*)(smem + WH_OFF + (L*18 + dir*9 + st)*512 + LB*8) = w;
    }
    for (int idx = t; idx < 192; idx += BLOCK) {   // pred10: A[c][k] = Wout[c][k]
        int ks = idx >> 6, LB = idx & 63;
        int c = LB & 15, k0 = 16*ks + 4*(LB >> 4);
        half4 w = PACK4(0.f, 0.f, 0.f, 0.f);
        if (c < 10) {
            float4 w4 = *(const float4*)(Wout + c*48 + k0);
            w = PACK4(w4.x, w4.y, w4.z, w4.w);
        }
        *(half4*)(smem + WOUTP_OFF + ks*512 + LB*8) = w;
    }
    for (int idx = t; idx < 192; idx += BLOCK) {   // td10: A[m][c] = Wout[c][m]
        int tm = idx >> 6, LB = idx & 63;
        int m = 16*tm + (LB & 15), c0 = 4*(LB >> 4);
        float w0 = (c0+0 < 10) ? Wout[(c0+0)*48 + m] : 0.f;
        float w1 = (c0+1 < 10) ? Wout[(c0+1)*48 + m] : 0.f;
        float w2 = (c0+2 < 10) ? Wout[(c0+2)*48 + m] : 0.f;
        float w3 = (c0+3 < 10) ? Wout[(c0+3)*48 + m] : 0.f;
        *(half4*)(smem + WOUTT_OFF + tm*512 + LB*8) = PACK4(w0, w1, w2, w3);
    }
    for (int idx = t; idx < 432; idx += BLOCK)
        *(float*)(smem + BH_OFF + idx*4) = bh[idx];
    if (t < 16)
        *(float*)(smem + BOUT_OFF + t*4) = (t < 10) ? bout[t] : 0.f;
    __syncthreads();   // last barrier -- settling loop is barrier-free

    // hoist output-layer frags + bias to registers
    half4 WP[3], WT[3];
    #pragma unroll
    for (int k = 0; k < 3; ++k) {
        WP[k] = *(const half4*)(smem + WOUTP_OFF + k*512 + lane*8);
        WT[k] = *(const half4*)(smem + WOUTT_OFF + k*512 + lane*8);
    }
    f32x4 bo4 = *(const f32x4*)(smem + BOUT_OFF + b*16);
    const int tg = target[samp];

    // ======== forward init layers 1..9 ========
    FWD(1); FWD(2); FWD(3); FWD(4); FWD(5); FWD(6); FWD(7); FWD(8); FWD(9);

    // ======== settling ========
    #pragma unroll 1
    for (int s = 0; s < 20; ++s) {
        float ep[12];
        #pragma unroll
        for (int q = 0; q < 12; ++q) ep[q] = v[0][q] - a0r[q];

        LAYER_STEP(1); LAYER_STEP(2); LAYER_STEP(3); LAYER_STEP(4); LAYER_STEP(5);
        LAYER_STEP(6); LAYER_STEP(7); LAYER_STEP(8); LAYER_STEP(9);

        // ---- output layer (single f16: LR-damped), fully lane-local ----
        {
            half4 B9[3];
            #pragma unroll
            for (int ks = 0; ks < 3; ++ks)
                B9[ks] = PACK4(v[9][ks*4+0], v[9][ks*4+1], v[9][ks*4+2], v[9][ks*4+3]);
            f32x4 accP = bo4;
            #pragma unroll
            for (int ks = 0; ks < 3; ++ks)
                accP = MFMA16(WP[ks], B9[ks], accP, 0, 0, 0);
            // e10 for classes 4b+q of own sample (zero for class >= 10)
            int c0 = 4*b;
            float e0 = (c0+0 < 10) ? (((c0+0 == tg) ? 1.f : 0.f) - accP[0]) : 0.f;
            float e1 = (c0+1 < 10) ? (((c0+1 == tg) ? 1.f : 0.f) - accP[1]) : 0.f;
            float e2 = (c0+2 < 10) ? (((c0+2 == tg) ? 1.f : 0.f) - accP[2]) : 0.f;
            float e3 = (c0+3 < 10) ? (((c0+3 == tg) ? 1.f : 0.f) - accP[3]) : 0.f;
            half4 eB = PACK4(e0, e1, e2, e3);   // B[k=class 4b+j][own sample]
            float td10[12];
            #pragma unroll
            for (int tm = 0; tm < 3; ++tm) {
                f32x4 a2 = {0.f, 0.f, 0.f, 0.f};
                a2 = MFMA16(WT[tm], eB, a2, 0, 0, 0);
                #pragma unroll
                for (int q = 0; q < 4; ++q) td10[tm*4+q] = a2[q];
            }
            #pragma unroll
            for (int q = 0; q < 12; ++q) {
                float nv = v[9][q] - LR*(ep[q] - td10[q]);
                v[9][q] = fminf(fmaxf(nv, -10.f), 10.f);
            }
        }
    }

    // ======== write V: out[L][sample][comp], comps 16t+4b..+3 contiguous ========
    #pragma unroll
    for (int L2 = 0; L2 < 10; ++L2) {
        #pragma unroll
        for (int tt = 0; tt < 3; ++tt) {
            f32x4 w4 = { v[L2][tt*4+0], v[L2][tt*4+1], v[L2][tt*4+2], v[L2][tt*4+3] };
            *(f32x4*)(out + (size_t)L2*65536*48 + (size_t)samp*48 + tt*16 + 4*b) = w4;
        }
    }
}

extern "C" void kernel_launch(void* const* d_in, const int* in_sizes, int n_in,
                              void* d_out, int out_size, void* d_ws, size_t ws_size,
                              hipStream_t stream) {
    const float* x      = (const float*)d_in[0];
    const int*   target = (const int*)d_in[1];
    const float* W0     = (const float*)d_in[2];
    const float* b0     = (const float*)d_in[3];
    const float* Wh     = (const float*)d_in[4];
    const float* bh     = (const float*)d_in[5];
    const float* Wout   = (const float*)d_in[6];
    const float* bout   = (const float*)d_in[7];
    float* out = (float*)d_out;

    hipFuncSetAttribute((const void*)pcnet_kernel,
                        hipFuncAttributeMaxDynamicSharedMemorySize, LDS_BYTES);

    dim3 grid(65536/64);    // 1024 blocks, 64 samples each
    dim3 block(BLOCK);      // 4 waves x 16 samples
    pcnet_kernel<<<grid, block, LDS_BYTES, stream>>>(x, target, W0, b0, Wh, bh, Wout, bout, out);
}

// Round 10
// 581.146 us; speedup vs baseline: 5.1940x; 2.0395x over previous
//
#include <hip/hip_runtime.h>
#include <stdint.h>

typedef __attribute__((ext_vector_type(4))) _Float16 half4;
typedef __attribute__((ext_vector_type(4))) float f32x4;

#define LR 0.1f
#define BLOCK 256
#define MFMA16 __builtin_amdgcn_mfma_f32_16x16x16f16
#define SCHEDB __builtin_amdgcn_sched_barrier

// LDS byte offsets
#define WH_OFF    0         // [9L][2dir][9 subtile(tm*3+ks)][64 lane][8B] = 82944
#define WOUTP_OFF 82944     // pred10 A-frags: 3 ks x 512 = 1536
#define WOUTT_OFF 84480     // td10  A-frags: 3 tm x 512 = 1536
#define BH_OFF    86016     // bh f32 9*48 = 1728
#define BOUT_OFF  87744     // bout f32 padded 16 = 64
#define A0_OFF    87808     // per-thread a0 slot: 256 x 52 B = 13312
#define LDS_BYTES 101120

extern __shared__ unsigned char smem[];

// build half4 from 4 floats, RNE scalar casts (SSA vector inserts, no alloca)
#define PACK4(S0,S1,S2,S3) __extension__({ \
  half4 _b; \
  _b[0] = (_Float16)(S0); _b[1] = (_Float16)(S1); \
  _b[2] = (_Float16)(S2); _b[3] = (_Float16)(S3); \
  _b; })

// pred-direction 48x48 matvec, f16 2-term split on values (B), bias from bh LDS.
// ks-outer: 3 f32x4 accumulators live (the result), one B hi/lo pair in flight.
#define PRED48(SRC, WOFF, LIDX, DST) do { \
  f32x4 _a0 = *(const f32x4*)(smem + BH_OFF + ((LIDX)*48 +  0)*4 + b*16); \
  f32x4 _a1 = *(const f32x4*)(smem + BH_OFF + ((LIDX)*48 + 16)*4 + b*16); \
  f32x4 _a2 = *(const f32x4*)(smem + BH_OFF + ((LIDX)*48 + 32)*4 + b*16); \
  _Pragma("unroll") \
  for (int _ks = 0; _ks < 3; ++_ks) { \
    _Float16 _h0 = (_Float16)SRC[_ks*4+0]; \
    _Float16 _h1 = (_Float16)SRC[_ks*4+1]; \
    _Float16 _h2 = (_Float16)SRC[_ks*4+2]; \
    _Float16 _h3 = (_Float16)SRC[_ks*4+3]; \
    half4 _bh; _bh[0]=_h0; _bh[1]=_h1; _bh[2]=_h2; _bh[3]=_h3; \
    half4 _bl; \
    _bl[0] = (_Float16)(SRC[_ks*4+0] - (float)_h0); \
    _bl[1] = (_Float16)(SRC[_ks*4+1] - (float)_h1); \
    _bl[2] = (_Float16)(SRC[_ks*4+2] - (float)_h2); \
    _bl[3] = (_Float16)(SRC[_ks*4+3] - (float)_h3); \
    half4 _A0 = *(const half4*)(smem + (WOFF) + (0*3+_ks)*512 + lane*8); \
    half4 _A1 = *(const half4*)(smem + (WOFF) + (1*3+_ks)*512 + lane*8); \
    half4 _A2 = *(const half4*)(smem + (WOFF) + (2*3+_ks)*512 + lane*8); \
    _a0 = MFMA16(_A0, _bh, _a0, 0, 0, 0); _a0 = MFMA16(_A0, _bl, _a0, 0, 0, 0); \
    _a1 = MFMA16(_A1, _bh, _a1, 0, 0, 0); _a1 = MFMA16(_A1, _bl, _a1, 0, 0, 0); \
    _a2 = MFMA16(_A2, _bh, _a2, 0, 0, 0); _a2 = MFMA16(_A2, _bl, _a2, 0, 0, 0); \
  } \
  _Pragma("unroll") \
  for (int _q = 0; _q < 4; ++_q) { \
    DST[0+_q] = _a0[_q]; DST[4+_q] = _a1[_q]; DST[8+_q] = _a2[_q]; \
  } \
} while(0)

// td-direction 48x48 matvec, single f16 (LR-damped), no bias.
#define TD48(SRC, WOFF, DST) do { \
  f32x4 _a0 = {0.f,0.f,0.f,0.f}, _a1 = {0.f,0.f,0.f,0.f}, _a2 = {0.f,0.f,0.f,0.f}; \
  _Pragma("unroll") \
  for (int _ks = 0; _ks < 3; ++_ks) { \
    half4 _bb = PACK4(SRC[_ks*4+0], SRC[_ks*4+1], SRC[_ks*4+2], SRC[_ks*4+3]); \
    half4 _A0 = *(const half4*)(smem + (WOFF) + (0*3+_ks)*512 + lane*8); \
    half4 _A1 = *(const half4*)(smem + (WOFF) + (1*3+_ks)*512 + lane*8); \
    half4 _A2 = *(const half4*)(smem + (WOFF) + (2*3+_ks)*512 + lane*8); \
    _a0 = MFMA16(_A0, _bb, _a0, 0, 0, 0); \
    _a1 = MFMA16(_A1, _bb, _a1, 0, 0, 0); \
    _a2 = MFMA16(_A2, _bb, _a2, 0, 0, 0); \
  } \
  _Pragma("unroll") \
  for (int _q = 0; _q < 4; ++_q) { \
    DST[0+_q] = _a0[_q]; DST[4+_q] = _a1[_q]; DST[8+_q] = _a2[_q]; \
  } \
} while(0)

#define LAYER_STEP(I) do { \
  float _pre[12], _err[12], _me[12], _td[12]; \
  PRED48(v[(I)-1], WH_OFF + ((I)-1)*9216, (I)-1, _pre); \
  _Pragma("unroll") \
  for (int _q = 0; _q < 12; ++_q) { \
    float _rl = fmaxf(_pre[_q], 0.f); \
    _err[_q] = v[I][_q] - _rl; \
    _me[_q] = (_pre[_q] > 0.f) ? _err[_q] : 0.f; \
  } \
  TD48(_me, WH_OFF + ((I)-1)*9216 + 4608, _td); \
  _Pragma("unroll") \
  for (int _q = 0; _q < 12; ++_q) { \
    float _nv = v[(I)-1][_q] - LR*(ep[_q] - _td[_q]); \
    v[(I)-1][_q] = fminf(fmaxf(_nv, -10.f), 10.f); \
    ep[_q] = _err[_q]; \
  } \
  SCHEDB(0); \
} while(0)

#define FWD(I) do { \
  float _pre[12]; \
  PRED48(v[(I)-1], WH_OFF + ((I)-1)*9216, (I)-1, _pre); \
  _Pragma("unroll") \
  for (int _q = 0; _q < 12; ++_q) v[I][_q] = fmaxf(_pre[_q], 0.f); \
  SCHEDB(0); \
} while(0)

__global__ __launch_bounds__(BLOCK) __attribute__((amdgpu_waves_per_eu(1, 1)))
void pcnet_kernel(const float* __restrict__ x, const int* __restrict__ target,
                  const float* __restrict__ W0, const float* __restrict__ b0,
                  const float* __restrict__ Wh, const float* __restrict__ bh,
                  const float* __restrict__ Wout, const float* __restrict__ bout,
                  float* __restrict__ out)
{
    const int t = threadIdx.x;
    const int lane = t & 63;
    const int wv = t >> 6;
    const int n = lane & 15;    // own sample within wave
    const int b = lane >> 4;    // comp sub-block 0..3 (owns comps 16t+4b+q)

    const int bsamp0 = blockIdx.x*64 + wv*16;   // wave's first sample
    const int samp = bsamp0 + n;

    float* a0l = (float*)(smem + A0_OFF + t*52);   // per-thread a0 slot (13 words: conflict-free)

    // ======== phase 0: a0 = relu(x@W0^T + b0) via MFMA; x is B-operand ========
    f32x4 acc0[3];
    #pragma unroll
    for (int tm = 0; tm < 3; ++tm) acc0[tm] = (f32x4){0.f, 0.f, 0.f, 0.f};

    const float* xrow = x + (size_t)samp*784;
    for (int ch = 0; ch < 7; ++ch) {
        __syncthreads();
        for (int idx = t; idx < 1344; idx += BLOCK) {
            int st = idx >> 6, LB = idx & 63;
            int tm = st / 7, ksl = st - tm*7;
            int row = 16*tm + (LB & 15);
            int col = ch*112 + ksl*16 + 4*(LB >> 4);
            float4 w4 = *(const float4*)(W0 + row*784 + col);
            *(half4*)(smem + (tm*7+ksl)*512 + LB*8) = PACK4(w4.x, w4.y, w4.z, w4.w);
        }
        __syncthreads();
        #pragma unroll
        for (int ksl = 0; ksl < 7; ++ksl) {
            float4 xv = *(const float4*)(xrow + ch*112 + ksl*16 + 4*b);
            half4 xb = PACK4(xv.x, xv.y, xv.z, xv.w);
            #pragma unroll
            for (int tm = 0; tm < 3; ++tm) {
                half4 A = *(const half4*)(smem + (tm*7+ksl)*512 + lane*8);
                acc0[tm] = MFMA16(A, xb, acc0[tm], 0, 0, 0);
            }
        }
    }

    float v[10][12];
    #pragma unroll
    for (int tm = 0; tm < 3; ++tm) {
        float4 bb = *(const float4*)(b0 + 16*tm + 4*b);
        float bs[4] = {bb.x, bb.y, bb.z, bb.w};
        #pragma unroll
        for (int q = 0; q < 4; ++q) {
            float val = fmaxf(acc0[tm][q] + bs[q], 0.f);
            v[0][tm*4+q] = val;
            a0l[tm*4+q] = val;          // a0 lives in LDS, not registers
        }
    }
    __syncthreads();   // phase-0 reads done before WH staging overwrites

    // ======== stage weight A-frags (f16, K16 layout, conflict-free 8B/lane) ====
    for (int idx = t; idx < 10368; idx += BLOCK) {
        int L = idx / 1152;
        int r1 = idx - L*1152;
        int dir = r1 / 576;
        int r2 = r1 - dir*576;
        int st = r2 >> 6, LB = r2 & 63;
        int tm = st / 3, ks = st - tm*3;
        int m  = 16*tm + (LB & 15);
        int k0 = 16*ks + 4*(LB >> 4);
        half4 w;
        if (dir == 0) {   // pred: A[m][k] = Wh[L][m][k]
            float4 w4 = *(const float4*)(Wh + L*2304 + m*48 + k0);
            w = PACK4(w4.x, w4.y, w4.z, w4.w);
        } else {          // td:   A[m][k] = Wh[L][k][m]
            const float* p = Wh + L*2304 + k0*48 + m;
            w = PACK4(p[0], p[48], p[96], p[144]);
        }
        *(half4*)(smem + WH_OFF + (L*18 + dir*9 + st)*512 + LB*8) = w;
    }
    for (int idx = t; idx < 192; idx += BLOCK) {   // pred10: A[c][k] = Wout[c][k]
        int ks = idx >> 6, LB = idx & 63;
        int c = LB & 15, k0 = 16*ks + 4*(LB >> 4);
        half4 w = PACK4(0.f, 0.f, 0.f, 0.f);
        if (c < 10) {
            float4 w4 = *(const float4*)(Wout + c*48 + k0);
            w = PACK4(w4.x, w4.y, w4.z, w4.w);
        }
        *(half4*)(smem + WOUTP_OFF + ks*512 + LB*8) = w;
    }
    for (int idx = t; idx < 192; idx += BLOCK) {   // td10: A[m][c] = Wout[c][m]
        int tm = idx >> 6, LB = idx & 63;
        int m = 16*tm + (LB & 15), c0 = 4*(LB >> 4);
        float w0 = (c0+0 < 10) ? Wout[(c0+0)*48 + m] : 0.f;
        float w1 = (c0+1 < 10) ? Wout[(c0+1)*48 + m] : 0.f;
        float w2 = (c0+2 < 10) ? Wout[(c0+2)*48 + m] : 0.f;
        float w3 = (c0+3 < 10) ? Wout[(c0+3)*48 + m] : 0.f;
        *(half4*)(smem + WOUTT_OFF + tm*512 + LB*8) = PACK4(w0, w1, w2, w3);
    }
    for (int idx = t; idx < 432; idx += BLOCK)
        *(float*)(smem + BH_OFF + idx*4) = bh[idx];
    if (t < 16)
        *(float*)(smem + BOUT_OFF + t*4) = (t < 10) ? bout[t] : 0.f;
    __syncthreads();   // last barrier -- settling loop is barrier-free

    const int tg = target[samp];

    // ======== forward init layers 1..9 ========
    FWD(1); FWD(2); FWD(3); FWD(4); FWD(5); FWD(6); FWD(7); FWD(8); FWD(9);

    // ======== settling ========
    #pragma unroll 1
    for (int s = 0; s < 20; ++s) {
        float ep[12];
        #pragma unroll
        for (int q = 0; q < 12; ++q) ep[q] = v[0][q] - a0l[q];

        LAYER_STEP(1); LAYER_STEP(2); LAYER_STEP(3); LAYER_STEP(4); LAYER_STEP(5);
        LAYER_STEP(6); LAYER_STEP(7); LAYER_STEP(8); LAYER_STEP(9);

        // ---- output layer (single f16: LR-damped), fully lane-local ----
        {
            half4 B9[3];
            #pragma unroll
            for (int ks = 0; ks < 3; ++ks)
                B9[ks] = PACK4(v[9][ks*4+0], v[9][ks*4+1], v[9][ks*4+2], v[9][ks*4+3]);
            f32x4 accP = *(const f32x4*)(smem + BOUT_OFF + b*16);
            #pragma unroll
            for (int ks = 0; ks < 3; ++ks) {
                half4 WPk = *(const half4*)(smem + WOUTP_OFF + ks*512 + lane*8);
                accP = MFMA16(WPk, B9[ks], accP, 0, 0, 0);
            }
            // e10 for classes 4b+q of own sample (zero for class >= 10)
            int c0 = 4*b;
            float e0 = (c0+0 < 10) ? (((c0+0 == tg) ? 1.f : 0.f) - accP[0]) : 0.f;
            float e1 = (c0+1 < 10) ? (((c0+1 == tg) ? 1.f : 0.f) - accP[1]) : 0.f;
            float e2 = (c0+2 < 10) ? (((c0+2 == tg) ? 1.f : 0.f) - accP[2]) : 0.f;
            float e3 = (c0+3 < 10) ? (((c0+3 == tg) ? 1.f : 0.f) - accP[3]) : 0.f;
            half4 eB = PACK4(e0, e1, e2, e3);   // B[k=class 4b+j][own sample]
            float td10[12];
            #pragma unroll
            for (int tm = 0; tm < 3; ++tm) {
                half4 WTk = *(const half4*)(smem + WOUTT_OFF + tm*512 + lane*8);
                f32x4 a2 = {0.f, 0.f, 0.f, 0.f};
                a2 = MFMA16(WTk, eB, a2, 0, 0, 0);
                #pragma unroll
                for (int q = 0; q < 4; ++q) td10[tm*4+q] = a2[q];
            }
            #pragma unroll
            for (int q = 0; q < 12; ++q) {
                float nv = v[9][q] - LR*(ep[q] - td10[q]);
                v[9][q] = fminf(fmaxf(nv, -10.f), 10.f);
            }
            SCHEDB(0);
        }
    }

    // ======== write V: out[L][sample][comp], comps 16t+4b..+3 contiguous ========
    #pragma unroll
    for (int L2 = 0; L2 < 10; ++L2) {
        #pragma unroll
        for (int tt = 0; tt < 3; ++tt) {
            f32x4 w4 = { v[L2][tt*4+0], v[L2][tt*4+1], v[L2][tt*4+2], v[L2][tt*4+3] };
            *(f32x4*)(out + (size_t)L2*65536*48 + (size_t)samp*48 + tt*16 + 4*b) = w4;
        }
    }
}

extern "C" void kernel_launch(void* const* d_in, const int* in_sizes, int n_in,
                              void* d_out, int out_size, void* d_ws, size_t ws_size,
                              hipStream_t stream) {
    const float* x      = (const float*)d_in[0];
    const int*   target = (const int*)d_in[1];
    const float* W0     = (const float*)d_in[2];
    const float* b0     = (const float*)d_in[3];
    const float* Wh     = (const float*)d_in[4];
    const float* bh     = (const float*)d_in[5];
    const float* Wout   = (const float*)d_in[6];
    const float* bout   = (const float*)d_in[7];
    float* out = (float*)d_out;

    hipFuncSetAttribute((const void*)pcnet_kernel,
                        hipFuncAttributeMaxDynamicSharedMemorySize, LDS_BYTES);

    dim3 grid(65536/64);    // 1024 blocks, 64 samples each
    dim3 block(BLOCK);      // 4 waves x 16 samples
    pcnet_kernel<<<grid, block, LDS_BYTES, stream>>>(x, target, W0, b0, Wh, bh, Wout, bout, out);
}